// Round 13
// baseline (875.062 us; speedup 1.0000x reference)
//
#include <hip/hip_runtime.h>
#include <hip/hip_bf16.h>
#include <cstdint>
#include <cstddef>

#define TTOK   4096
#define DIM_   2048
#define INTER_ 1408
#define NEXP   16
#define SINTER_ 2816
#define BM 128
#define BN 128
#define HK 32                           /* pipeline half-K */
#define MAXROWS (TTOK*2 + NEXP*BM)      /* 10240 padded routed slots */
#define MAXMT   (TTOK*2/BM + NEXP)      /* 80 worst-case M tiles */

typedef unsigned short u16;
typedef __attribute__((ext_vector_type(8))) short short8;
typedef __attribute__((ext_vector_type(4))) float f32x4;

#define AS3P(p) ((__attribute__((address_space(3))) void*)(p))
#define AS1P(p) ((const __attribute__((address_space(1))) void*)(p))

__device__ __forceinline__ void gll16(const void* g, void* l) {
    __builtin_amdgcn_global_load_lds(AS1P(g), AS3P(l), 16, 0, 0);
}

__device__ __forceinline__ u16 f2bf(float f) {
    __hip_bfloat16 h = __float2bfloat16(f);
    union { __hip_bfloat16 h; u16 u; } c; c.h = h; return c.u;
}

__device__ __forceinline__ unsigned pk2(float a, float b) {
    unsigned r;
    asm("v_cvt_pk_bf16_f32 %0, %1, %2" : "=v"(r) : "v"(a), "v"(b));
    return r;
}

__device__ __forceinline__ int4 pack8(float4 a, float4 b) {
    int4 r;
    r.x = (int)pk2(a.x, a.y);
    r.y = (int)pk2(a.z, a.w);
    r.z = (int)pk2(b.x, b.y);
    r.w = (int)pk2(b.z, b.w);
    return r;
}

// pipeline fences: wait for oldest loads (counted, never 0 mid-loop), then
// barrier; memory-clobber asm keeps C++ ds_reads from hoisting (rule #18).
#define PWAIT(NLIT) do { \
    asm volatile("s_waitcnt vmcnt(" #NLIT ")" ::: "memory"); \
    __builtin_amdgcn_s_barrier(); \
    asm volatile("" ::: "memory"); \
} while (0)
#define PDONE() do { \
    asm volatile("" ::: "memory"); \
    __builtin_amdgcn_s_barrier(); \
    asm volatile("" ::: "memory"); \
} while (0)

// ---------------- small kernels ----------------

// misc layout (ints): [0..16) counts, [16..32) fill, [32..48) base,
//                     [48..128) tile_expert, [128..208) tile_row0
__global__ void init_kernel(int* perm_rt, float* pw_rt, int* misc, int* zrow) {
    int i = blockIdx.x * 256 + threadIdx.x;
    if (i < MAXROWS) { perm_rt[i] = -1; pw_rt[i] = 0.f; }
    if (i < 32)      misc[i] = 0;
    if (i < 1024)    zrow[i] = 0;      // 4 KB zero page (= one 2048-elem bf16 row)
}

// ---- merged f32->bf16 conversion: all 6 weights + x in ONE launch ----
#define NW8  ((long)NEXP * INTER_ * DIM_ / 8)
#define NSW8 ((long)SINTER_ * DIM_ / 8)
#define NX8  ((long)TTOK * DIM_ / 8)
#define TOT8 (3 * NW8 + 3 * NSW8 + NX8)

__global__ void cvt_all_kernel(
    const float* __restrict__ w1, const float* __restrict__ w2,
    const float* __restrict__ w3, const float* __restrict__ sw1,
    const float* __restrict__ sw2, const float* __restrict__ sw3,
    const float* __restrict__ x,
    u16* __restrict__ w1b, u16* __restrict__ w2b, u16* __restrict__ w3b,
    u16* __restrict__ sw1b, u16* __restrict__ sw2b, u16* __restrict__ sw3b,
    u16* __restrict__ xb)
{
    const long stride = (long)gridDim.x * 256;
    for (long i = (long)blockIdx.x * 256 + threadIdx.x; i < TOT8; i += stride) {
        const float* s; u16* d; long off;
        if      (i <     NW8)              { s = w1;  d = w1b;  off = i; }
        else if (i < 2 * NW8)              { s = w2;  d = w2b;  off = i - NW8; }
        else if (i < 3 * NW8)              { s = w3;  d = w3b;  off = i - 2 * NW8; }
        else if (i < 3 * NW8 + NSW8)       { s = sw1; d = sw1b; off = i - 3 * NW8; }
        else if (i < 3 * NW8 + 2 * NSW8)   { s = sw2; d = sw2b; off = i - 3 * NW8 - NSW8; }
        else if (i < 3 * NW8 + 3 * NSW8)   { s = sw3; d = sw3b; off = i - 3 * NW8 - 2 * NSW8; }
        else                               { s = x;   d = xb;   off = i - 3 * NW8 - 3 * NSW8; }
        const float4* s4 = (const float4*)(s + off * 8);
        float4 a = s4[0], b = s4[1];
        *(int4*)(d + off * 8) = pack8(a, b);
    }
}

__global__ void gate_kernel(const float* __restrict__ x, const float* __restrict__ gw,
                            int* __restrict__ topi, float* __restrict__ topw,
                            int* __restrict__ misc) {
    int t = blockIdx.x;
    int lane = threadIdx.x;
    const float* xr = x + (size_t)t * DIM_;
    float acc[NEXP];
#pragma unroll
    for (int e = 0; e < NEXP; e++) acc[e] = 0.f;
#pragma unroll
    for (int i = 0; i < 8; i++) {
        int k = i * 256 + lane * 4;
        float4 xv = *(const float4*)(xr + k);
#pragma unroll
        for (int e = 0; e < NEXP; e++) {
            float4 gv = *(const float4*)(gw + (size_t)e * DIM_ + k);
            acc[e] += xv.x * gv.x + xv.y * gv.y + xv.z * gv.z + xv.w * gv.w;
        }
    }
#pragma unroll
    for (int e = 0; e < NEXP; e++) {
        float v = acc[e];
        for (int off = 32; off > 0; off >>= 1) v += __shfl_down(v, off);
        acc[e] = v;
    }
    if (lane == 0) {
        float m = acc[0];
#pragma unroll
        for (int e = 1; e < NEXP; e++) m = fmaxf(m, acc[e]);
        float p[NEXP]; float s = 0.f;
#pragma unroll
        for (int e = 0; e < NEXP; e++) { p[e] = __expf(acc[e] - m); s += p[e]; }
        int i0 = 0; float v0 = p[0];
#pragma unroll
        for (int e = 1; e < NEXP; e++) if (p[e] > v0) { v0 = p[e]; i0 = e; }
        int i1 = -1; float v1 = -1.f;
#pragma unroll
        for (int e = 0; e < NEXP; e++) if (e != i0 && p[e] > v1) { v1 = p[e]; i1 = e; }
        float inv = 1.f / s;
        topi[2 * t] = i0; topi[2 * t + 1] = i1;
        topw[2 * t] = v0 * inv; topw[2 * t + 1] = v1 * inv;
        atomicAdd(&misc[i0], 1);
        atomicAdd(&misc[i1], 1);
    }
}

__global__ void scan_kernel(int* misc) {
    int* counts = misc;
    int* base   = misc + 32;
    int* te     = misc + 48;
    int* tr     = misc + 128;
    int b = 0, tt = 0;
    for (int e = 0; e < NEXP; e++) {
        int c = counts[e];
        int nt = (c + BM - 1) >> 7;
        base[e] = b;
        for (int i = 0; i < nt; i++) { te[tt] = e; tr[tt] = b + i * BM; tt++; }
        b += nt * BM;
    }
    for (int i = tt; i < MAXMT; i++) te[i] = -1;
}

__global__ void scatter_kernel(const int* __restrict__ topi, const float* __restrict__ topw,
                               int* __restrict__ misc, int* __restrict__ perm,
                               float* __restrict__ pw) {
    int t = blockIdx.x * 256 + threadIdx.x;
    if (t >= TTOK) return;
    int* fill = misc + 16;
    int* base = misc + 32;
#pragma unroll
    for (int k = 0; k < 2; k++) {
        int e = topi[2 * t + k];
        int pos = base[e] + atomicAdd(&fill[e], 1);
        perm[pos] = t;
        pw[pos] = topw[2 * t + k];
    }
}

// ---------------- fused h13 GEMM — 2-deep counted-vmcnt pipeline ----------------
// Half-K = 32; two half-buffers per matrix (6 x 8 KB = 48 KB, same as R12's
// BK=64 single-buf -> occupancy unchanged at 2 blocks/CU). Per half-step:
//   vmcnt(6) [oldest half's 6 loads done; next half's stay in flight]
//   barrier; 24 dual-MFMA from buf[h&1]; barrier; issue half h+2 -> buf[h&1]
// Loads get ~2 compute phases (~780cy) to cover ~500cy HBM/L2 latency; the
// R10-R12 loop drained vmcnt(0) 0 cycles after issue (full latency exposed,
// MfmaUtil capped at 28%).
// Staging/swizzle = R8-verified BK=32 scheme (0 bank conflicts):
//   store: lane l -> row l>>2, pre-swizzled GLOBAL chunk (l&3)^((l>>3)&3)
//   read : frag chunk kg ^ ((col>>1)&3)
// XCD-chunked jn-major 1D grid (T1). (256,2) REQUIRED (dual acc ~232 regs).

template<bool GROUPED>
__global__ __launch_bounds__(256, 2) void gemm_h13_k(
    const u16* __restrict__ Xb,
    const u16* __restrict__ W1b, const u16* __restrict__ W3b,
    u16* __restrict__ H,
    const int* __restrict__ perm,
    const int* __restrict__ te, const int* __restrict__ tr,
    const u16* __restrict__ zrow,
    int N, int K, int nt_m, int chunk)
{
    const int q = (blockIdx.x & 7) * chunk + (blockIdx.x >> 3);
    if (q >= nt_m * (N / BN)) return;
    const int jn = q / nt_m, im = q % nt_m;
    int e, slot0;
    if (GROUPED) { e = te[im]; if (e < 0) return; slot0 = tr[im]; }
    else         { e = 0; slot0 = im * BM; }
    const int n0 = jn * BN;
    const u16* W1 = W1b + (size_t)e * N * K;
    const u16* W3 = W3b + (size_t)e * N * K;

    __shared__ __align__(16) u16 As[2][BM * HK];
    __shared__ __align__(16) u16 B1s[2][BM * HK];
    __shared__ __align__(16) u16 B3s[2][BM * HK];

    const int tid = threadIdx.x;
    const int lane = tid & 63, wid = tid >> 6;
    const int wr = wid >> 1, wc = wid & 1;
    const int col = lane & 15, kg = lane >> 4;

    // staging: lane l -> row l>>2 (16 rows/inst), pre-swz chunk (l&3)^((l>>3)&3)
    const int lr = lane >> 2;
    const int kb = ((lane & 3) ^ ((lane >> 3) & 3)) * 8;   // u16 elems
    const int ar0 = wid * 32 + lr, ar1 = ar0 + 16;
    const u16* ga0;
    const u16* ga1;
    if (GROUPED) {
        const int ta0 = perm[slot0 + ar0];
        const int ta1 = perm[slot0 + ar1];
        ga0 = (ta0 >= 0 ? Xb + (size_t)ta0 * K : zrow) + kb;
        ga1 = (ta1 >= 0 ? Xb + (size_t)ta1 * K : zrow) + kb;
    } else {
        ga0 = Xb + (size_t)(slot0 + ar0) * K + kb;
        ga1 = Xb + (size_t)(slot0 + ar1) * K + kb;
    }
    const u16* gb1a = W1 + (size_t)(n0 + ar0) * K + kb;
    const u16* gb1b = W1 + (size_t)(n0 + ar1) * K + kb;
    const u16* gb3a = W3 + (size_t)(n0 + ar0) * K + kb;
    const u16* gb3b = W3 + (size_t)(n0 + ar1) * K + kb;
    const int lo0 = (wid * 32) * HK;
    const int lo1 = (wid * 32 + 16) * HK;

    const int sw = (col >> 1) & 3;           // read-side swizzle key

    f32x4 acc1[4][4] = {};
    f32x4 acc3[4][4] = {};

    auto ISSUE = [&](int h) {
        const int b = h & 1;
        const int ko = h * HK;
        gll16(ga0 + ko, &As[b][lo0]);
        gll16(ga1 + ko, &As[b][lo1]);
        gll16(gb1a + ko, &B1s[b][lo0]);
        gll16(gb1b + ko, &B1s[b][lo1]);
        gll16(gb3a + ko, &B3s[b][lo0]);
        gll16(gb3b + ko, &B3s[b][lo1]);
    };

    const int nh = K / HK;
    ISSUE(0);
    ISSUE(1);

    for (int h = 0; h < nh; ++h) {
        if (h + 1 < nh) PWAIT(6); else PWAIT(0);

        const int b = h & 1;
        const u16* Ac  = As[b];
        const u16* B1c = B1s[b];
        const u16* B3c = B3s[b];

        short8 a[4];
#pragma unroll
        for (int mi = 0; mi < 4; mi++)
            a[mi] = *(const short8*)(Ac + (wr * 64 + mi * 16 + col) * HK + ((kg ^ sw) * 8));
#pragma unroll
        for (int ni = 0; ni < 4; ni++) {
            const int off = (wc * 64 + ni * 16 + col) * HK + ((kg ^ sw) * 8);
            short8 v1 = *(const short8*)(B1c + off);
            short8 v3 = *(const short8*)(B3c + off);
#pragma unroll
            for (int mi = 0; mi < 4; mi++) {
                acc1[mi][ni] = __builtin_amdgcn_mfma_f32_16x16x32_bf16(a[mi], v1, acc1[mi][ni], 0, 0, 0);
                acc3[mi][ni] = __builtin_amdgcn_mfma_f32_16x16x32_bf16(a[mi], v3, acc3[mi][ni], 0, 0, 0);
            }
        }

        PDONE();
        if (h + 2 < nh) ISSUE(h + 2);
    }

    // epilogue: h = silu(acc1) * acc3, store bf16 (padding rows produce 0)
#pragma unroll
    for (int mi = 0; mi < 4; mi++) {
#pragma unroll
        for (int j = 0; j < 4; j++) {
            int row = slot0 + wr * 64 + mi * 16 + kg * 4 + j;
#pragma unroll
            for (int ni = 0; ni < 4; ni++) {
                float v1 = acc1[mi][ni][j];
                float v3 = acc3[mi][ni][j];
                float hv = v1 / (1.f + __expf(-v1)) * v3;
                int c = n0 + wc * 64 + ni * 16 + col;
                H[(size_t)row * N + c] = f2bf(hv);
            }
        }
    }
}

// ---------------- out GEMM — same pipeline, single acc, (256,4) ----------------
// 4 buffers x 8 KB = 32 KB; regs ~56V+64A = 120 <= 128 cap at 4 waves/EU
// (single-acc; R5's spill was the DUAL-acc kernel at this cap).

template<bool ATOMIC>
__global__ __launch_bounds__(256, 4) void gemm_out_k(
    const u16* __restrict__ Hm,
    const u16* __restrict__ W2b,
    float* __restrict__ Out,
    const int* __restrict__ perm, const float* __restrict__ pw,
    const int* __restrict__ te, const int* __restrict__ tr,
    int K, int nt_m, int chunk)
{
    const int q = (blockIdx.x & 7) * chunk + (blockIdx.x >> 3);
    if (q >= nt_m * (DIM_ / BN)) return;
    const int jn = q / nt_m, im = q % nt_m;
    int e, slot0;
    if (ATOMIC) { e = te[im]; if (e < 0) return; slot0 = tr[im]; }
    else        { e = 0; slot0 = im * BM; }
    const int n0 = jn * BN;
    const u16* W2 = W2b + (size_t)e * DIM_ * K;

    __shared__ __align__(16) u16 As[2][BM * HK];
    __shared__ __align__(16) u16 Bs[2][BM * HK];

    const int tid = threadIdx.x;
    const int lane = tid & 63, wid = tid >> 6;
    const int wr = wid >> 1, wc = wid & 1;
    const int col = lane & 15, kg = lane >> 4;

    const int lr = lane >> 2;
    const int kb = ((lane & 3) ^ ((lane >> 3) & 3)) * 8;
    const int ar0 = wid * 32 + lr, ar1 = ar0 + 16;
    const u16* ga0 = Hm + (size_t)(slot0 + ar0) * K + kb;
    const u16* ga1 = Hm + (size_t)(slot0 + ar1) * K + kb;
    const u16* gb0 = W2 + (size_t)(n0 + ar0) * K + kb;
    const u16* gb1 = W2 + (size_t)(n0 + ar1) * K + kb;
    const int lo0 = (wid * 32) * HK;
    const int lo1 = (wid * 32 + 16) * HK;

    const int sw = (col >> 1) & 3;

    f32x4 acc[4][4] = {};

    auto ISSUE = [&](int h) {
        const int b = h & 1;
        const int ko = h * HK;
        gll16(ga0 + ko, &As[b][lo0]);
        gll16(ga1 + ko, &As[b][lo1]);
        gll16(gb0 + ko, &Bs[b][lo0]);
        gll16(gb1 + ko, &Bs[b][lo1]);
    };

    const int nh = K / HK;
    ISSUE(0);
    ISSUE(1);

    for (int h = 0; h < nh; ++h) {
        if (h + 1 < nh) PWAIT(4); else PWAIT(0);

        const int b = h & 1;
        const u16* Ac = As[b];
        const u16* Bc = Bs[b];

        short8 a[4];
#pragma unroll
        for (int mi = 0; mi < 4; mi++)
            a[mi] = *(const short8*)(Ac + (wr * 64 + mi * 16 + col) * HK + ((kg ^ sw) * 8));
#pragma unroll
        for (int ni = 0; ni < 4; ni++) {
            short8 bv = *(const short8*)(Bc + (wc * 64 + ni * 16 + col) * HK + ((kg ^ sw) * 8));
#pragma unroll
            for (int mi = 0; mi < 4; mi++)
                acc[mi][ni] = __builtin_amdgcn_mfma_f32_16x16x32_bf16(a[mi], bv, acc[mi][ni], 0, 0, 0);
        }

        PDONE();
        if (h + 2 < nh) ISSUE(h + 2);
    }

#pragma unroll
    for (int mi = 0; mi < 4; mi++) {
#pragma unroll
        for (int j = 0; j < 4; j++) {
            int rloc = wr * 64 + mi * 16 + kg * 4 + j;
            int slot = slot0 + rloc;
            if (ATOMIC) {
                int token = perm[slot];
                if (token < 0) continue;
                float w = pw[slot];
#pragma unroll
                for (int ni = 0; ni < 4; ni++) {
                    int c = n0 + wc * 64 + ni * 16 + col;
                    atomicAdd(&Out[(size_t)token * DIM_ + c], acc[mi][ni][j] * w);
                }
            } else {
#pragma unroll
                for (int ni = 0; ni < 4; ni++) {
                    int c = n0 + wc * 64 + ni * 16 + col;
                    Out[(size_t)slot * DIM_ + c] = acc[mi][ni][j];
                }
            }
        }
    }
}

// ---------------- launch ----------------

extern "C" void kernel_launch(void* const* d_in, const int* in_sizes, int n_in,
                              void* d_out, int out_size, void* d_ws, size_t ws_size,
                              hipStream_t stream) {
    (void)in_sizes; (void)n_in; (void)out_size; (void)ws_size;
    const float* x   = (const float*)d_in[0];
    const float* gw  = (const float*)d_in[1];
    const float* w1  = (const float*)d_in[2];
    const float* w2  = (const float*)d_in[3];
    const float* w3  = (const float*)d_in[4];
    const float* sw1 = (const float*)d_in[5];
    const float* sw2 = (const float*)d_in[6];
    const float* sw3 = (const float*)d_in[7];
    float* out = (float*)d_out;

    char* ws = (char*)d_ws;
    size_t off = 0;
    auto take = [&](size_t bytes) -> void* {
        void* p = ws + off;
        off += (bytes + 255) & ~(size_t)255;
        return p;
    };
    const size_t nHB = ((size_t)MAXROWS * INTER_ > (size_t)TTOK * SINTER_)
                       ? (size_t)MAXROWS * INTER_ : (size_t)TTOK * SINTER_;
    u16*   xb      = (u16*)take((size_t)TTOK * DIM_ * 2);
    u16*   hbuf    = (u16*)take(nHB * 2);
    int*   perm_rt = (int*)take((size_t)MAXROWS * 4);
    float* pw_rt   = (float*)take((size_t)MAXROWS * 4);
    int*   topi    = (int*)take((size_t)TTOK * 2 * 4);
    float* topw    = (float*)take((size_t)TTOK * 2 * 4);
    int*   misc    = (int*)take(1024);
    int*   zrow    = (int*)take(4096);
    const size_t nW  = (size_t)NEXP * INTER_ * DIM_;     // w1 / w2 / w3 each
    const size_t nSW = (size_t)SINTER_ * DIM_;           // sw1 / sw2 / sw3 each
    u16* w1b  = (u16*)take(nW * 2);
    u16* w2b  = (u16*)take(nW * 2);
    u16* w3b  = (u16*)take(nW * 2);
    u16* sw1b = (u16*)take(nSW * 2);
    u16* sw2b = (u16*)take(nSW * 2);
    u16* sw3b = (u16*)take(nSW * 2);

    init_kernel<<<MAXROWS / 256, 256, 0, stream>>>(perm_rt, pw_rt, misc, zrow);
    // ONE merged conversion launch (weights + x)
    cvt_all_kernel<<<4096, 256, 0, stream>>>(w1, w2, w3, sw1, sw2, sw3, x,
                                             w1b, w2b, w3b, sw1b, sw2b, sw3b, xb);
    gate_kernel<<<TTOK, 64, 0, stream>>>(x, gw, topi, topw, misc);
    scan_kernel<<<1, 1, 0, stream>>>(misc);
    scatter_kernel<<<TTOK / 256, 256, 0, stream>>>(topi, topw, misc, perm_rt, pw_rt);

    auto grid8 = [](int total) { return ((total + 7) / 8) * 8; };
    auto chunk8 = [](int total) { return (total + 7) / 8; };

    const int ntm_sh = TTOK / BM;   // 32

    // shared expert
    {
        int total = ntm_sh * (SINTER_ / BN);
        gemm_h13_k<false><<<grid8(total), 256, 0, stream>>>(
            xb, sw1b, sw3b, hbuf, nullptr, nullptr, nullptr, (const u16*)zrow,
            SINTER_, DIM_, ntm_sh, chunk8(total));
    }
    {
        int total = ntm_sh * (DIM_ / BN);
        gemm_out_k<false><<<grid8(total), 256, 0, stream>>>(
            hbuf, sw2b, out, nullptr, nullptr, nullptr, nullptr,
            SINTER_, ntm_sh, chunk8(total));
    }
    // routed experts
    {
        int total = MAXMT * (INTER_ / BN);
        gemm_h13_k<true><<<grid8(total), 256, 0, stream>>>(
            xb, w1b, w3b, hbuf, perm_rt, misc + 48, misc + 128, (const u16*)zrow,
            INTER_, DIM_, MAXMT, chunk8(total));
    }
    {
        int total = MAXMT * (DIM_ / BN);
        gemm_out_k<true><<<grid8(total), 256, 0, stream>>>(
            hbuf, w2b, out, perm_rt, pw_rt, misc + 48, misc + 128,
            INTER_, MAXMT, chunk8(total));
    }
}

// Round 14
// 818.762 us; speedup vs baseline: 1.0688x; 1.0688x over previous
//
#include <hip/hip_runtime.h>
#include <hip/hip_bf16.h>
#include <cstdint>
#include <cstddef>

#define TTOK   4096
#define DIM_   2048
#define INTER_ 1408
#define NEXP   16
#define SINTER_ 2816
#define BM 128
#define BN 128
#define BK 64
#define MAXROWS (TTOK*2 + NEXP*BM)      /* 10240 padded routed slots */
#define MAXMT   (TTOK*2/BM + NEXP)      /* 80 worst-case M tiles */

#define NT_SH_H  ((TTOK/BM) * (SINTER_/BN))   /* 704 shared h13 tiles  */
#define NT_RT_H  (MAXMT * (INTER_/BN))        /* 880 routed h13 tiles  */
#define NT_H     (NT_SH_H + NT_RT_H)          /* 1584 */
#define NT_SH_O  ((TTOK/BM) * (DIM_/BN))      /* 512 shared out tiles  */
#define NT_RT_O  (MAXMT * (DIM_/BN))          /* 1280 routed out tiles */
#define NT_O     (NT_SH_O + NT_RT_O)          /* 1792 */

typedef unsigned short u16;
typedef __attribute__((ext_vector_type(8))) short short8;
typedef __attribute__((ext_vector_type(4))) float f32x4;

#define AS3P(p) ((__attribute__((address_space(3))) void*)(p))
#define AS1P(p) ((const __attribute__((address_space(1))) void*)(p))

__device__ __forceinline__ void gll16(const void* g, void* l) {
    __builtin_amdgcn_global_load_lds(AS1P(g), AS3P(l), 16, 0, 0);
}

__device__ __forceinline__ u16 f2bf(float f) {
    __hip_bfloat16 h = __float2bfloat16(f);
    union { __hip_bfloat16 h; u16 u; } c; c.h = h; return c.u;
}

__device__ __forceinline__ unsigned pk2(float a, float b) {
    unsigned r;
    asm("v_cvt_pk_bf16_f32 %0, %1, %2" : "=v"(r) : "v"(a), "v"(b));
    return r;
}

__device__ __forceinline__ int4 pack8(float4 a, float4 b) {
    int4 r;
    r.x = (int)pk2(a.x, a.y);
    r.y = (int)pk2(a.z, a.w);
    r.z = (int)pk2(b.x, b.y);
    r.w = (int)pk2(b.z, b.w);
    return r;
}

// ---------------- merged conversion + init + out-zero (one launch) ----------------
#define NW8  ((long)NEXP * INTER_ * DIM_ / 8)
#define NSW8 ((long)SINTER_ * DIM_ / 8)
#define NX8  ((long)TTOK * DIM_ / 8)
#define TOT8 (3 * NW8 + 3 * NSW8 + NX8)

__global__ void cvt_all_kernel(
    const float* __restrict__ w1, const float* __restrict__ w2,
    const float* __restrict__ w3, const float* __restrict__ sw1,
    const float* __restrict__ sw2, const float* __restrict__ sw3,
    const float* __restrict__ x,
    u16* __restrict__ w1b, u16* __restrict__ w2b, u16* __restrict__ w3b,
    u16* __restrict__ sw1b, u16* __restrict__ sw2b, u16* __restrict__ sw3b,
    u16* __restrict__ xb,
    int* __restrict__ perm_rt, float* __restrict__ pw_rt,
    int* __restrict__ misc, int* __restrict__ zrow,
    float* __restrict__ outz)
{
    const long stride = (long)gridDim.x * 256;
    const long gid = (long)blockIdx.x * 256 + threadIdx.x;

    // init section (was init_kernel)
    if (gid < MAXROWS) { perm_rt[gid] = -1; pw_rt[gid] = 0.f; }
    if (gid < 32)      misc[gid] = 0;
    if (gid < 1024)    zrow[gid] = 0;
    // zero d_out (both out passes atomicAdd now)
    for (long i = gid; i < (long)TTOK * DIM_ / 4; i += stride)
        *(float4*)(outz + i * 4) = make_float4(0.f, 0.f, 0.f, 0.f);

    // conversion section (compile-time segment bounds -> constant if-chain)
    for (long i = gid; i < TOT8; i += stride) {
        const float* s; u16* d; long off;
        if      (i <     NW8)              { s = w1;  d = w1b;  off = i; }
        else if (i < 2 * NW8)              { s = w2;  d = w2b;  off = i - NW8; }
        else if (i < 3 * NW8)              { s = w3;  d = w3b;  off = i - 2 * NW8; }
        else if (i < 3 * NW8 + NSW8)       { s = sw1; d = sw1b; off = i - 3 * NW8; }
        else if (i < 3 * NW8 + 2 * NSW8)   { s = sw2; d = sw2b; off = i - 3 * NW8 - NSW8; }
        else if (i < 3 * NW8 + 3 * NSW8)   { s = sw3; d = sw3b; off = i - 3 * NW8 - 2 * NSW8; }
        else                               { s = x;   d = xb;   off = i - 3 * NW8 - 3 * NSW8; }
        const float4* s4 = (const float4*)(s + off * 8);
        float4 a = s4[0], b = s4[1];
        *(int4*)(d + off * 8) = pack8(a, b);
    }
}

__global__ void gate_kernel(const float* __restrict__ x, const float* __restrict__ gw,
                            int* __restrict__ topi, float* __restrict__ topw,
                            int* __restrict__ misc) {
    int t = blockIdx.x;
    int lane = threadIdx.x;
    const float* xr = x + (size_t)t * DIM_;
    float acc[NEXP];
#pragma unroll
    for (int e = 0; e < NEXP; e++) acc[e] = 0.f;
#pragma unroll
    for (int i = 0; i < 8; i++) {
        int k = i * 256 + lane * 4;
        float4 xv = *(const float4*)(xr + k);
#pragma unroll
        for (int e = 0; e < NEXP; e++) {
            float4 gv = *(const float4*)(gw + (size_t)e * DIM_ + k);
            acc[e] += xv.x * gv.x + xv.y * gv.y + xv.z * gv.z + xv.w * gv.w;
        }
    }
#pragma unroll
    for (int e = 0; e < NEXP; e++) {
        float v = acc[e];
        for (int off = 32; off > 0; off >>= 1) v += __shfl_down(v, off);
        acc[e] = v;
    }
    if (lane == 0) {
        float m = acc[0];
#pragma unroll
        for (int e = 1; e < NEXP; e++) m = fmaxf(m, acc[e]);
        float p[NEXP]; float s = 0.f;
#pragma unroll
        for (int e = 0; e < NEXP; e++) { p[e] = __expf(acc[e] - m); s += p[e]; }
        int i0 = 0; float v0 = p[0];
#pragma unroll
        for (int e = 1; e < NEXP; e++) if (p[e] > v0) { v0 = p[e]; i0 = e; }
        int i1 = -1; float v1 = -1.f;
#pragma unroll
        for (int e = 0; e < NEXP; e++) if (e != i0 && p[e] > v1) { v1 = p[e]; i1 = e; }
        float inv = 1.f / s;
        topi[2 * t] = i0; topi[2 * t + 1] = i1;
        topw[2 * t] = v0 * inv; topw[2 * t + 1] = v1 * inv;
        atomicAdd(&misc[i0], 1);
        atomicAdd(&misc[i1], 1);
    }
}

__global__ void scan_kernel(int* misc) {
    int* counts = misc;
    int* base   = misc + 32;
    int* te     = misc + 48;
    int* tr     = misc + 128;
    int b = 0, tt = 0;
    for (int e = 0; e < NEXP; e++) {
        int c = counts[e];
        int nt = (c + BM - 1) >> 7;
        base[e] = b;
        for (int i = 0; i < nt; i++) { te[tt] = e; tr[tt] = b + i * BM; tt++; }
        b += nt * BM;
    }
    for (int i = tt; i < MAXMT; i++) te[i] = -1;
}

__global__ void scatter_kernel(const int* __restrict__ topi, const float* __restrict__ topw,
                               int* __restrict__ misc, int* __restrict__ perm,
                               float* __restrict__ pw) {
    int t = blockIdx.x * 256 + threadIdx.x;
    if (t >= TTOK) return;
    int* fill = misc + 16;
    int* base = misc + 32;
#pragma unroll
    for (int k = 0; k < 2; k++) {
        int e = topi[2 * t + k];
        int pos = base[e] + atomicAdd(&fill[e], 1);
        perm[pos] = t;
        pw[pos] = topw[2 * t + k];
    }
}

// ---------------- MERGED h13 GEMM (shared + routed in one launch) ----------------
// R12-verified loop: bf16, gll16 staging, BK=64, 2 barriers/K-step.
// q < 704: shared tile (N=2816, eIdx=16, A rows direct);
// q >= 704: routed tile (N=1408, e from table, A rows via perm, -1 -> zrow).
// Weight arenas adjacent: w1b..sw1b contiguous, so eoff = eIdx*INTER_*DIM_
// with eIdx=16 lands exactly on the shared weights.
// Swizzle (R8/R10-verified, 0 conflicts): store global chunk (l&7)^(l>>3),
// read chunk cc^(col&7). (256,2) REQUIRED (dual acc; R5 spill at (256,4)).

__global__ __launch_bounds__(256, 2) void gemm_h13_m(
    const u16* __restrict__ Xb,
    const u16* __restrict__ W1b, const u16* __restrict__ W3b,
    u16* __restrict__ HS, u16* __restrict__ HR,
    const int* __restrict__ perm,
    const int* __restrict__ te, const int* __restrict__ tr,
    const u16* __restrict__ zrow,
    int K, int chunk)
{
    const int q = (blockIdx.x & 7) * chunk + (blockIdx.x >> 3);
    if (q >= NT_H) return;
    int im, jn, N, slot0; size_t eoff; u16* H; bool gather;
    if (q < NT_SH_H) {
        im = q % (TTOK / BM); jn = q / (TTOK / BM);
        N = SINTER_; slot0 = im * BM; eoff = (size_t)NEXP * INTER_ * DIM_;
        H = HS; gather = false;
    } else {
        int q2 = q - NT_SH_H;
        im = q2 % MAXMT; jn = q2 / MAXMT;
        int e = te[im]; if (e < 0) return;
        slot0 = tr[im]; N = INTER_; eoff = (size_t)e * INTER_ * DIM_;
        H = HR; gather = true;
    }
    const int n0 = jn * BN;
    const u16* W1 = W1b + eoff;
    const u16* W3 = W3b + eoff;

    __shared__ __align__(16) u16 As[BM * BK];
    __shared__ __align__(16) u16 B1s[BM * BK];
    __shared__ __align__(16) u16 B3s[BM * BK];

    const int tid = threadIdx.x;
    const int lane = tid & 63, wid = tid >> 6;
    const int wr = wid >> 1, wc = wid & 1;
    const int col = lane & 15, kg = lane >> 4;

    const int lr8 = lane >> 3;
    const int kb  = ((lane & 7) ^ lr8) * 8;          // u16 elems, pre-swizzled
    const int rB0 = wid * 32 + lr8;
    const u16* gA[4];
#pragma unroll
    for (int i = 0; i < 4; i++) {
        int row = slot0 + rB0 + 8 * i;
        if (gather) {
            int ta = perm[row];
            gA[i] = (ta >= 0 ? Xb + (size_t)ta * K : zrow) + kb;
        } else {
            gA[i] = Xb + (size_t)row * K + kb;
        }
    }
    const u16* g1 = W1 + (size_t)(n0 + rB0) * K + kb;
    const u16* g3 = W3 + (size_t)(n0 + rB0) * K + kb;

    const int ldsI = (wid * 32) * BK;
    const int swr = col & 7;

    f32x4 acc1[4][4] = {};
    f32x4 acc3[4][4] = {};

    for (int k0 = 0; k0 < K; k0 += BK) {
#pragma unroll
        for (int i = 0; i < 4; i++) {
            gll16(gA[i] + k0, As + ldsI + i * 8 * BK);
            gll16(g1 + (size_t)(8 * i) * K + k0, B1s + ldsI + i * 8 * BK);
            gll16(g3 + (size_t)(8 * i) * K + k0, B3s + ldsI + i * 8 * BK);
        }
        __syncthreads();

        short8 a[4][2];
#pragma unroll
        for (int mi = 0; mi < 4; mi++)
#pragma unroll
            for (int t = 0; t < 2; t++) {
                int cc = kg + 4 * t;
                a[mi][t] = *(const short8*)(As + (wr * 64 + mi * 16 + col) * BK + ((cc ^ swr) * 8));
            }
#pragma unroll
        for (int t = 0; t < 2; t++) {
#pragma unroll
            for (int ni = 0; ni < 4; ni++) {
                int cc = kg + 4 * t;
                int off = (wc * 64 + ni * 16 + col) * BK + ((cc ^ swr) * 8);
                short8 v1 = *(const short8*)(B1s + off);
                short8 v3 = *(const short8*)(B3s + off);
#pragma unroll
                for (int mi = 0; mi < 4; mi++) {
                    acc1[mi][ni] = __builtin_amdgcn_mfma_f32_16x16x32_bf16(a[mi][t], v1, acc1[mi][ni], 0, 0, 0);
                    acc3[mi][ni] = __builtin_amdgcn_mfma_f32_16x16x32_bf16(a[mi][t], v3, acc3[mi][ni], 0, 0, 0);
                }
            }
        }
        __syncthreads();
    }

#pragma unroll
    for (int mi = 0; mi < 4; mi++) {
#pragma unroll
        for (int j = 0; j < 4; j++) {
            int row = slot0 + wr * 64 + mi * 16 + kg * 4 + j;
#pragma unroll
            for (int ni = 0; ni < 4; ni++) {
                float v1 = acc1[mi][ni][j];
                float v3 = acc3[mi][ni][j];
                float hv = v1 / (1.f + __expf(-v1)) * v3;
                int c = n0 + wc * 64 + ni * 16 + col;
                H[(size_t)row * N + c] = f2bf(hv);
            }
        }
    }
}

// ---------------- MERGED out GEMM (shared + routed in one launch) ----------------
// d_out pre-zeroed; BOTH paths atomicAdd (shared stores would race with
// routed adds inside one launch). Shared: token=slot, w=1, K=2816, A=HS.
// Routed: token=perm[slot], w=pw, K=1408, A=HR. (256,3) as in R12.

__global__ __launch_bounds__(256, 3) void gemm_out_m(
    const u16* __restrict__ HS, const u16* __restrict__ HR,
    const u16* __restrict__ W2b,
    float* __restrict__ Out,
    const int* __restrict__ perm, const float* __restrict__ pw,
    const int* __restrict__ te, const int* __restrict__ tr,
    int chunk)
{
    const int q = (blockIdx.x & 7) * chunk + (blockIdx.x >> 3);
    if (q >= NT_O) return;
    int im, jn, K, slot0; size_t eoff; const u16* A; bool gather;
    if (q < NT_SH_O) {
        im = q % (TTOK / BM); jn = q / (TTOK / BM);
        K = SINTER_; slot0 = im * BM; eoff = (size_t)NEXP * INTER_ * DIM_;
        A = HS; gather = false;
    } else {
        int q2 = q - NT_SH_O;
        im = q2 % MAXMT; jn = q2 / MAXMT;
        int e = te[im]; if (e < 0) return;
        slot0 = tr[im]; K = INTER_; eoff = (size_t)e * INTER_ * DIM_;
        A = HR; gather = true;
    }
    const int n0 = jn * BN;
    const u16* W2 = W2b + eoff;

    __shared__ __align__(16) u16 As[BM * BK];
    __shared__ __align__(16) u16 Bs[BM * BK];

    const int tid = threadIdx.x;
    const int lane = tid & 63, wid = tid >> 6;
    const int wr = wid >> 1, wc = wid & 1;
    const int col = lane & 15, kg = lane >> 4;

    const int lr8 = lane >> 3;
    const int kb  = ((lane & 7) ^ lr8) * 8;
    const int rB0 = wid * 32 + lr8;
    const u16* gA = A + (size_t)(slot0 + rB0) * K + kb;
    const u16* gB = W2 + (size_t)(n0 + rB0) * K + kb;
    const int ldsI = (wid * 32) * BK;
    const int swr = col & 7;

    f32x4 acc[4][4] = {};

    for (int k0 = 0; k0 < K; k0 += BK) {
#pragma unroll
        for (int i = 0; i < 4; i++) {
            gll16(gA + (size_t)(8 * i) * K + k0, As + ldsI + i * 8 * BK);
            gll16(gB + (size_t)(8 * i) * K + k0, Bs + ldsI + i * 8 * BK);
        }
        __syncthreads();

        short8 a[4][2];
#pragma unroll
        for (int mi = 0; mi < 4; mi++)
#pragma unroll
            for (int t = 0; t < 2; t++) {
                int cc = kg + 4 * t;
                a[mi][t] = *(const short8*)(As + (wr * 64 + mi * 16 + col) * BK + ((cc ^ swr) * 8));
            }
#pragma unroll
        for (int t = 0; t < 2; t++) {
#pragma unroll
            for (int ni = 0; ni < 4; ni++) {
                int cc = kg + 4 * t;
                int off = (wc * 64 + ni * 16 + col) * BK + ((cc ^ swr) * 8);
                short8 bv = *(const short8*)(Bs + off);
#pragma unroll
                for (int mi = 0; mi < 4; mi++)
                    acc[mi][ni] = __builtin_amdgcn_mfma_f32_16x16x32_bf16(a[mi][t], bv, acc[mi][ni], 0, 0, 0);
            }
        }
        __syncthreads();
    }

#pragma unroll
    for (int mi = 0; mi < 4; mi++) {
#pragma unroll
        for (int j = 0; j < 4; j++) {
            int rloc = wr * 64 + mi * 16 + kg * 4 + j;
            int slot = slot0 + rloc;
            int token; float w;
            if (gather) {
                token = perm[slot];
                if (token < 0) continue;
                w = pw[slot];
            } else {
                token = slot;
                w = 1.f;
            }
#pragma unroll
            for (int ni = 0; ni < 4; ni++) {
                int c = n0 + wc * 64 + ni * 16 + col;
                atomicAdd(&Out[(size_t)token * DIM_ + c], acc[mi][ni][j] * w);
            }
        }
    }
}

// ---------------- launch ----------------

extern "C" void kernel_launch(void* const* d_in, const int* in_sizes, int n_in,
                              void* d_out, int out_size, void* d_ws, size_t ws_size,
                              hipStream_t stream) {
    (void)in_sizes; (void)n_in; (void)out_size; (void)ws_size;
    const float* x   = (const float*)d_in[0];
    const float* gw  = (const float*)d_in[1];
    const float* w1  = (const float*)d_in[2];
    const float* w2  = (const float*)d_in[3];
    const float* w3  = (const float*)d_in[4];
    const float* sw1 = (const float*)d_in[5];
    const float* sw2 = (const float*)d_in[6];
    const float* sw3 = (const float*)d_in[7];
    float* out = (float*)d_out;

    char* ws = (char*)d_ws;
    size_t off = 0;
    auto take = [&](size_t bytes) -> void* {
        void* p = ws + off;
        off += (bytes + 255) & ~(size_t)255;
        return p;
    };
    u16*   xb      = (u16*)take((size_t)TTOK * DIM_ * 2);
    u16*   hbufS   = (u16*)take((size_t)TTOK * SINTER_ * 2);    // shared h
    u16*   hbufR   = (u16*)take((size_t)MAXROWS * INTER_ * 2);  // routed h
    int*   perm_rt = (int*)take((size_t)MAXROWS * 4);
    float* pw_rt   = (float*)take((size_t)MAXROWS * 4);
    int*   topi    = (int*)take((size_t)TTOK * 2 * 4);
    float* topw    = (float*)take((size_t)TTOK * 2 * 4);
    int*   misc    = (int*)take(1024);
    int*   zrow    = (int*)take(4096);
    const size_t nW  = (size_t)NEXP * INTER_ * DIM_;     // per routed-weight arena
    const size_t nSW = (size_t)SINTER_ * DIM_;           // per shared-weight arena
    // ADJACENCY REQUIRED: w*b immediately followed by sw*b (sizes are
    // 256-multiples so take() inserts no padding) -> eIdx=16 addresses shared.
    u16* w1b  = (u16*)take(nW * 2);
    u16* sw1b = (u16*)take(nSW * 2);
    u16* w3b  = (u16*)take(nW * 2);
    u16* sw3b = (u16*)take(nSW * 2);
    u16* w2b  = (u16*)take(nW * 2);
    u16* sw2b = (u16*)take(nSW * 2);

    // 1) merged conversion + init + out-zero
    cvt_all_kernel<<<4096, 256, 0, stream>>>(w1, w2, w3, sw1, sw2, sw3, x,
                                             w1b, w2b, w3b, sw1b, sw2b, sw3b, xb,
                                             perm_rt, pw_rt, misc, zrow, out);
    // 2) gate / 3) scan / 4) scatter
    gate_kernel<<<TTOK, 64, 0, stream>>>(x, gw, topi, topw, misc);
    scan_kernel<<<1, 1, 0, stream>>>(misc);
    scatter_kernel<<<TTOK / 256, 256, 0, stream>>>(topi, topw, misc, perm_rt, pw_rt);

    // 5) merged h13 (shared 704 tiles + routed 880 tiles)
    gemm_h13_m<<<NT_H, 256, 0, stream>>>(
        xb, w1b, w3b, hbufS, hbufR, perm_rt, misc + 48, misc + 128,
        (const u16*)zrow, DIM_, NT_H / 8);

    // 6) merged out (shared 512 + routed 1280), atomic onto zeroed d_out
    gemm_out_m<<<NT_O, 256, 0, stream>>>(
        hbufS, hbufR, w2b, out, perm_rt, pw_rt, misc + 48, misc + 128,
        NT_O / 8);
}